// Round 1
// baseline (152.202 us; speedup 1.0000x reference)
//
#include <hip/hip_runtime.h>

#define N_PART 512
#define H_DIM 32
#define M_DIM 4
#define L_DIM 8
#define N_STEPS (M_DIM * (L_DIM - 1))   // 28
#define N_JOBS (N_STEPS + M_DIM)        // 32
#define NBLK (N_JOBS * 32)              // 1024 (32 rowgroups of 16 rows)
#define NCELL 2048
#define RMAX 10.0f
#define TSCALE ((float)NCELL / RMAX)    // 204.8
#define TWO_LOG2E 2.8853900817779268f

// ws layout: [0, 24KB) float3 table; [24KB, 48KB) partials double[1024][3];
// [48KB, +4) unsigned ticket
#define TAB_FLOATS (NCELL * 3)
#define TAB_BYTES (TAB_FLOATS * 4)
#define PART_BYTES (NBLK * 3 * 8)

// ---------------------------------------------------------------------------
// Build the r-table: cell c holds {St, Sg, Sl} at r = c/TSCALE.
// Also zeroes the ticket counter used by the fused last-block finalize.
__global__ __launch_bounds__(256)
void tfl_tabgen(const float* __restrict__ p1, const float* __restrict__ pb1,
                const float* __restrict__ p2, float* __restrict__ tab,
                unsigned* __restrict__ ticket) {
  if (blockIdx.x == 0 && threadIdx.x == 0) *ticket = 0u;
  const int c = blockIdx.x * 256 + threadIdx.x;
  if (c >= NCELL) return;
  const float r = (float)c * (RMAX / (float)NCELL);
  float St = 0.f, Sg = 0.f, Sl = 0.f;
  for (int h = 0; h < H_DIM; ++h) {
    float p1h = p1[h], P2h = p2[h];
    float arg = TWO_LOG2E * fmaf(r, p1h, pb1[h]);
    float y = __builtin_amdgcn_exp2f(arg);
    float u = __builtin_amdgcn_rcpf(y + 1.0f);
    float t = fmaf(-2.0f, u, 1.0f);            // tanh
    float dd = fmaf(-u, u, u);                 // sech^2 / 4
    St = fmaf(t, P2h, St);
    Sg = fmaf(dd, 4.0f * p1h * P2h, Sg);       // dPhi
    Sl = fmaf(t * dd, -8.0f * p1h * p1h * P2h, Sl);  // d2Phi
  }
  tab[3 * c + 0] = St;
  tab[3 * c + 1] = Sg;
  tab[3 * c + 2] = Sl;
}

// ---------------------------------------------------------------------------
// Main: 1024 blocks = 32 jobs x 32 rowgroups(16 rows). 512 threads:
// 32 threads per row, each thread owns 16 j's. Accumulators are folded
// (pre-scaled by 1/N, V-terms merged) BEFORE the shuffle reduce: 4 vars,
// 5 xor steps, then one xor-32 to combine the wave's two rows.
// Finalize is fused: last block (atomic ticket) reduces all partials.
__global__ __launch_bounds__(512)
void tfl_main5(const float* __restrict__ data, const float* __restrict__ tsnap,
               const float* __restrict__ W1, const float* __restrict__ b1,
               const float* __restrict__ w2,
               const float* __restrict__ tab, double* __restrict__ partials,
               unsigned* __restrict__ ticket, float* __restrict__ out) {
  const int jb = blockIdx.x >> 5;
  const int rb = blockIdx.x & 31;
  const bool emode = (jb >= N_STEPS);
  const int m = emode ? (jb - N_STEPS) : jb / (L_DIM - 1);
  const int l = emode ? (L_DIM - 1) : jb % (L_DIM - 1);
  const float* X = data + (size_t)(m * L_DIM + l) * (N_PART * 2);

  __shared__ __align__(16) float sTab[TAB_FLOATS];  // 24 KB
  __shared__ __align__(16) float Xs[N_PART * 2];    // 4 KB
  __shared__ double sred[8][3];
  __shared__ unsigned sticket;

  const int tid = threadIdx.x;
#pragma unroll
  for (int q = 0; q < 3; ++q)
    ((float4*)sTab)[tid + 512 * q] = ((const float4*)tab)[tid + 512 * q];
  if (tid < 256) ((float4*)Xs)[tid] = ((const float4*)X)[tid];
  __syncthreads();

  const int wv = tid >> 6;
  const int ln = tid & 63;
  const int g = ln & 31;               // j-group id / h id (32 lanes per row)
  const int row = rb * 16 + (tid >> 5);
  const float xi0 = Xs[2 * row], xi1 = Xs[2 * row + 1];
  const float invN = 1.0f / N_PART;
  const float invN2 = invN * invN;

  // exact diagonal contribution (ki=0 cell, rs0 = rsq(1e-20)), removed later
  const float St0 = sTab[0], Sg0 = sTab[1], Sl0 = sTab[2];
  const float rs0 = __builtin_amdgcn_rsqf(1e-20f);

  // ----- pair loop: 16 j's per thread, one b96 gather per pair -----
  float aSt = 0.f, aGx = 0.f, aGy = 0.f, aLw = 0.f;
  const float2* Xs2 = (const float2*)Xs;
#pragma unroll 4
  for (int kk = 0; kk < 16; ++kk) {
    const int j = g + 32 * kk;
    float2 xj = Xs2[j];
    float dx = xi0 - xj.x;
    float dy = xi1 - xj.y;
    float sq = fmaxf(fmaf(dx, dx, dy * dy), 1e-20f);
    float rs = __builtin_amdgcn_rsqf(sq);
    float r = sq * rs;
    int ki = (int)fmaf(r, TSCALE, 0.5f);          // nearest cell
    ki = min(ki, NCELL - 1);
    const int b = 3 * ki;
    float Stv = sTab[b], Sgv = sTab[b + 1], Slv = sTab[b + 2];
    float tg = Sgv * rs;                          // dPhi / r
    aSt += Stv;                                   // Phi row sum (incl diag)
    aGx = fmaf(dx, tg, aGx);                      // dPhi * unit (diag: 0)
    aGy = fmaf(dy, tg, aGy);
    aLw += tg + Slv;                              // d2Phi + dPhi/r (incl diag)
  }

  // ----- V terms: h = g, 32 lanes per row -----
  float Vi, gVx, gVy, lapV;
  {
    float w10 = W1[g], w11 = W1[H_DIM + g], w2h = w2[g];
    float arg = TWO_LOG2E * fmaf(xi0, w10, fmaf(xi1, w11, b1[g]));
    float y = __builtin_amdgcn_exp2f(arg);
    float u = __builtin_amdgcn_rcpf(y + 1.0f);
    float t = fmaf(-2.0f, u, 1.0f);
    float dd = fmaf(-u, u, u);                    // sech^2 / 4
    Vi = t * w2h;
    float g4 = 4.0f * dd * w2h;                   // s * w2
    gVx = g4 * w10;
    gVy = g4 * w11;
    lapV = t * dd * (-8.0f * w2h) * fmaf(w10, w10, w11 * w11);
  }

  // ----- fold V + pair accumulators (all linear pre-squaring): 4 vars -----
  float eA = fmaf(aSt, invN2, Vi * invN);         // E contribution
  float gx = fmaf(aGx, invN, gVx);                // -drift_x
  float gy = fmaf(aGy, invN, gVy);                // -drift_y
  float lw = fmaf(aLw, invN, lapV);               // laplacian sum
#pragma unroll
  for (int sh = 1; sh < 32; sh <<= 1) {
    eA += __shfl_xor(eA, sh);
    gx += __shfl_xor(gx, sh);
    gy += __shfl_xor(gy, sh);
    lw += __shfl_xor(lw, sh);
  }
  // remove diagonal terms (replicated identically on all 32 lanes of the row)
  eA -= St0 * invN2;
  lw -= fmaf(Sg0, rs0, Sl0) * invN;

  float cJd = emode ? 0.f : fmaf(gx, gx, gy * gy);
  float cLap = emode ? 0.f : lw;
  // combine the wave's two rows: one xor-32 (values replicated per 32-group)
  cJd += __shfl_xor(cJd, 32);
  cLap += __shfl_xor(cLap, 32);
  eA += __shfl_xor(eA, 32);
  if (ln == 0) { sred[wv][0] = cJd; sred[wv][1] = cLap; sred[wv][2] = eA; }
  __syncthreads();
  if (tid == 0) {
    double sJd = 0, sLap = 0, sE = 0;
    for (int w = 0; w < 8; ++w) {
      sJd += sred[w][0]; sLap += sred[w][1]; sE += sred[w][2];
    }
    const double dN = 1.0 / N_PART;
    double j0 = 0.0, j1 = 0.0, j2 = 0.0;
    if (emode) {
      j2 = sE;                                    // +E(m, L-1) telescoped
    } else {
      double dt = (double)(tsnap[l + 1] - tsnap[l]);
      j0 = dt * dN * sJd;                         // J_diss partial
      j1 = dt * 0.01 * dN * sLap;                 // J_diff partial
      if (l == 0) j2 = -sE;                       // -E(m, 0) telescoped
    }
    partials[(size_t)blockIdx.x * 3 + 0] = j0;
    partials[(size_t)blockIdx.x * 3 + 1] = j1;
    partials[(size_t)blockIdx.x * 3 + 2] = j2;
  }

  // ----- fused finalize: last block to arrive reduces all partials -----
  __threadfence();                                // release partials (device)
  if (tid == 0) sticket = atomicAdd(ticket, 1u);
  __syncthreads();
  if (sticket == NBLK - 1) {
    __threadfence();                              // acquire others' partials
    double t0, t1, t2;
    {
      const double* p0 = partials + (size_t)tid * 3;
      const double* p1p = partials + (size_t)(tid + 512) * 3;
      t0 = p0[0] + p1p[0];
      t1 = p0[1] + p1p[1];
      t2 = p0[2] + p1p[2];
    }
#pragma unroll
    for (int sh = 1; sh < 64; sh <<= 1) {
      t0 += __shfl_xor(t0, sh);
      t1 += __shfl_xor(t1, sh);
      t2 += __shfl_xor(t2, sh);
    }
    if (ln == 0) { sred[wv][0] = t0; sred[wv][1] = t1; sred[wv][2] = t2; }
    __syncthreads();
    if (tid == 0) {
      double s0 = 0, s1 = 0, s2 = 0;
      for (int w = 0; w < 8; ++w) {
        s0 += sred[w][0]; s1 += sred[w][1]; s2 += sred[w][2];
      }
      double r = (s0 + s1 - 2.0 * s2) / (double)N_STEPS;
      out[0] = (float)(r * r);
    }
  }
}

// ---------------------------------------------------------------------------
extern "C" void kernel_launch(void* const* d_in, const int* in_sizes, int n_in,
                              void* d_out, int out_size, void* d_ws, size_t ws_size,
                              hipStream_t stream) {
  (void)in_sizes; (void)n_in; (void)out_size; (void)ws_size;
  const float* data  = (const float*)d_in[0];
  const float* tsnap = (const float*)d_in[1];
  const float* W1    = (const float*)d_in[2];
  const float* b1    = (const float*)d_in[3];
  const float* w2    = (const float*)d_in[4];
  // d_in[5] = b2 (cancels in telescoped dE)
  const float* p1    = (const float*)d_in[6];
  const float* pb1   = (const float*)d_in[7];
  const float* p2    = (const float*)d_in[8];
  // d_in[9] = pb2 (cancels in telescoped dE)
  float* tab = (float*)d_ws;
  double* partials = (double*)((char*)d_ws + TAB_BYTES);
  unsigned* ticket = (unsigned*)((char*)d_ws + TAB_BYTES + PART_BYTES);
  float* out = (float*)d_out;

  hipLaunchKernelGGL(tfl_tabgen, dim3(NCELL / 256), dim3(256), 0, stream,
                     p1, pb1, p2, tab, ticket);
  hipLaunchKernelGGL(tfl_main5, dim3(NBLK), dim3(512), 0, stream,
                     data, tsnap, W1, b1, w2, tab, partials, ticket, out);
}

// Round 2
// 22.048 us; speedup vs baseline: 6.9032x; 6.9032x over previous
//
#include <hip/hip_runtime.h>

#define N_PART 512
#define H_DIM 32
#define M_DIM 4
#define L_DIM 8
#define N_STEPS (M_DIM * (L_DIM - 1))   // 28
#define N_JOBS (N_STEPS + M_DIM)        // 32
#define NBLK (N_JOBS * 32)              // 1024 (32 rowgroups of 16 rows)
#define NCELL 2048
#define RMAX 10.0f
#define TSCALE ((float)NCELL / RMAX)    // 204.8
#define TWO_LOG2E 2.8853900817779268f

// ws layout: [0, 24KB) float3 table; [24KB, 48KB) partials double[1024][3]
#define TAB_FLOATS (NCELL * 3)
#define TAB_BYTES (TAB_FLOATS * 4)

// ---------------------------------------------------------------------------
// Build the r-table: cell c holds {St, Sg, Sl} at r = c/TSCALE.
__global__ __launch_bounds__(256)
void tfl_tabgen(const float* __restrict__ p1, const float* __restrict__ pb1,
                const float* __restrict__ p2, float* __restrict__ tab) {
  const int c = blockIdx.x * 256 + threadIdx.x;
  if (c >= NCELL) return;
  const float r = (float)c * (RMAX / (float)NCELL);
  float St = 0.f, Sg = 0.f, Sl = 0.f;
  for (int h = 0; h < H_DIM; ++h) {
    float p1h = p1[h], P2h = p2[h];
    float arg = TWO_LOG2E * fmaf(r, p1h, pb1[h]);
    float y = __builtin_amdgcn_exp2f(arg);
    float u = __builtin_amdgcn_rcpf(y + 1.0f);
    float t = fmaf(-2.0f, u, 1.0f);            // tanh
    float dd = fmaf(-u, u, u);                 // sech^2 / 4
    St = fmaf(t, P2h, St);
    Sg = fmaf(dd, 4.0f * p1h * P2h, Sg);       // dPhi
    Sl = fmaf(t * dd, -8.0f * p1h * p1h * P2h, Sl);  // d2Phi
  }
  tab[3 * c + 0] = St;
  tab[3 * c + 1] = Sg;
  tab[3 * c + 2] = Sl;
}

// ---------------------------------------------------------------------------
// Main: 1024 blocks = 32 jobs x 32 rowgroups(16 rows). 512 threads:
// 32 threads per row, each thread owns 16 j's. Accumulators are folded
// (pre-scaled by 1/N, V-terms merged) BEFORE the shuffle reduce: 4 vars,
// 5 xor steps, then one xor-32 to combine the wave's two rows.
// NO device-scope fences here (round-1 lesson: per-wave agent fences emit
// buffer_inv -> L2 invalidation storm -> 655 MB refetch, 145 us).
__global__ __launch_bounds__(512)
void tfl_main6(const float* __restrict__ data, const float* __restrict__ tsnap,
               const float* __restrict__ W1, const float* __restrict__ b1,
               const float* __restrict__ w2,
               const float* __restrict__ tab, double* __restrict__ partials) {
  const int jb = blockIdx.x >> 5;
  const int rb = blockIdx.x & 31;
  const bool emode = (jb >= N_STEPS);
  const int m = emode ? (jb - N_STEPS) : jb / (L_DIM - 1);
  const int l = emode ? (L_DIM - 1) : jb % (L_DIM - 1);
  const float* X = data + (size_t)(m * L_DIM + l) * (N_PART * 2);

  __shared__ __align__(16) float sTab[TAB_FLOATS];  // 24 KB
  __shared__ __align__(16) float Xs[N_PART * 2];    // 4 KB
  __shared__ double sred[8][3];

  const int tid = threadIdx.x;
#pragma unroll
  for (int q = 0; q < 3; ++q)
    ((float4*)sTab)[tid + 512 * q] = ((const float4*)tab)[tid + 512 * q];
  if (tid < 256) ((float4*)Xs)[tid] = ((const float4*)X)[tid];
  __syncthreads();

  const int wv = tid >> 6;
  const int ln = tid & 63;
  const int g = ln & 31;               // j-group id / h id (32 lanes per row)
  const int row = rb * 16 + (tid >> 5);
  const float xi0 = Xs[2 * row], xi1 = Xs[2 * row + 1];
  const float invN = 1.0f / N_PART;
  const float invN2 = invN * invN;

  // exact diagonal contribution (ki=0 cell, rs0 = rsq(1e-20)), removed later
  const float St0 = sTab[0], Sg0 = sTab[1], Sl0 = sTab[2];
  const float rs0 = __builtin_amdgcn_rsqf(1e-20f);

  // ----- pair loop: 16 j's per thread, one b96 gather per pair -----
  float aSt = 0.f, aGx = 0.f, aGy = 0.f, aLw = 0.f;
  const float2* Xs2 = (const float2*)Xs;
#pragma unroll 4
  for (int kk = 0; kk < 16; ++kk) {
    const int j = g + 32 * kk;
    float2 xj = Xs2[j];
    float dx = xi0 - xj.x;
    float dy = xi1 - xj.y;
    float sq = fmaxf(fmaf(dx, dx, dy * dy), 1e-20f);
    float rs = __builtin_amdgcn_rsqf(sq);
    float r = sq * rs;
    int ki = (int)fmaf(r, TSCALE, 0.5f);          // nearest cell
    ki = min(ki, NCELL - 1);
    const int b = 3 * ki;
    float Stv = sTab[b], Sgv = sTab[b + 1], Slv = sTab[b + 2];
    float tg = Sgv * rs;                          // dPhi / r
    aSt += Stv;                                   // Phi row sum (incl diag)
    aGx = fmaf(dx, tg, aGx);                      // dPhi * unit (diag: 0)
    aGy = fmaf(dy, tg, aGy);
    aLw += tg + Slv;                              // d2Phi + dPhi/r (incl diag)
  }

  // ----- V terms: h = g, 32 lanes per row -----
  float Vi, gVx, gVy, lapV;
  {
    float w10 = W1[g], w11 = W1[H_DIM + g], w2h = w2[g];
    float arg = TWO_LOG2E * fmaf(xi0, w10, fmaf(xi1, w11, b1[g]));
    float y = __builtin_amdgcn_exp2f(arg);
    float u = __builtin_amdgcn_rcpf(y + 1.0f);
    float t = fmaf(-2.0f, u, 1.0f);
    float dd = fmaf(-u, u, u);                    // sech^2 / 4
    Vi = t * w2h;
    float g4 = 4.0f * dd * w2h;                   // s * w2
    gVx = g4 * w10;
    gVy = g4 * w11;
    lapV = t * dd * (-8.0f * w2h) * fmaf(w10, w10, w11 * w11);
  }

  // ----- fold V + pair accumulators (all linear pre-squaring): 4 vars -----
  float eA = fmaf(aSt, invN2, Vi * invN);         // E contribution
  float gx = fmaf(aGx, invN, gVx);                // -drift_x
  float gy = fmaf(aGy, invN, gVy);                // -drift_y
  float lw = fmaf(aLw, invN, lapV);               // laplacian sum
#pragma unroll
  for (int sh = 1; sh < 32; sh <<= 1) {
    eA += __shfl_xor(eA, sh);
    gx += __shfl_xor(gx, sh);
    gy += __shfl_xor(gy, sh);
    lw += __shfl_xor(lw, sh);
  }
  // remove diagonal terms (replicated identically on all 32 lanes of the row)
  eA -= St0 * invN2;
  lw -= fmaf(Sg0, rs0, Sl0) * invN;

  float cJd = emode ? 0.f : fmaf(gx, gx, gy * gy);
  float cLap = emode ? 0.f : lw;
  // combine the wave's two rows: one xor-32 (values replicated per 32-group)
  cJd += __shfl_xor(cJd, 32);
  cLap += __shfl_xor(cLap, 32);
  eA += __shfl_xor(eA, 32);
  if (ln == 0) { sred[wv][0] = cJd; sred[wv][1] = cLap; sred[wv][2] = eA; }
  __syncthreads();
  if (tid == 0) {
    double sJd = 0, sLap = 0, sE = 0;
    for (int w = 0; w < 8; ++w) {
      sJd += sred[w][0]; sLap += sred[w][1]; sE += sred[w][2];
    }
    const double dN = 1.0 / N_PART;
    double j0 = 0.0, j1 = 0.0, j2 = 0.0;
    if (emode) {
      j2 = sE;                                    // +E(m, L-1) telescoped
    } else {
      double dt = (double)(tsnap[l + 1] - tsnap[l]);
      j0 = dt * dN * sJd;                         // J_diss partial
      j1 = dt * 0.01 * dN * sLap;                 // J_diff partial
      if (l == 0) j2 = -sE;                       // -E(m, 0) telescoped
    }
    partials[(size_t)blockIdx.x * 3 + 0] = j0;
    partials[(size_t)blockIdx.x * 3 + 1] = j1;
    partials[(size_t)blockIdx.x * 3 + 2] = j2;
  }
}

// ---------------------------------------------------------------------------
// 1 block, 512 threads: each thread sums 2 partial triplets, then a 6-step
// 64-lane shuffle reduce + 8-wave LDS combine (one barrier).
__global__ __launch_bounds__(512)
void tfl_finalize(const double* __restrict__ partials, float* __restrict__ out) {
  __shared__ double sred[8][3];
  const int tid = threadIdx.x;
  const int wv = tid >> 6;
  const int ln = tid & 63;
  const double* pa = partials + (size_t)tid * 3;
  const double* pb = partials + (size_t)(tid + 512) * 3;
  double t0 = pa[0] + pb[0];
  double t1 = pa[1] + pb[1];
  double t2 = pa[2] + pb[2];
#pragma unroll
  for (int sh = 1; sh < 64; sh <<= 1) {
    t0 += __shfl_xor(t0, sh);
    t1 += __shfl_xor(t1, sh);
    t2 += __shfl_xor(t2, sh);
  }
  if (ln == 0) { sred[wv][0] = t0; sred[wv][1] = t1; sred[wv][2] = t2; }
  __syncthreads();
  if (tid == 0) {
    double s0 = 0, s1 = 0, s2 = 0;
    for (int w = 0; w < 8; ++w) {
      s0 += sred[w][0]; s1 += sred[w][1]; s2 += sred[w][2];
    }
    double r = (s0 + s1 - 2.0 * s2) / (double)N_STEPS;
    out[0] = (float)(r * r);
  }
}

// ---------------------------------------------------------------------------
extern "C" void kernel_launch(void* const* d_in, const int* in_sizes, int n_in,
                              void* d_out, int out_size, void* d_ws, size_t ws_size,
                              hipStream_t stream) {
  (void)in_sizes; (void)n_in; (void)out_size; (void)ws_size;
  const float* data  = (const float*)d_in[0];
  const float* tsnap = (const float*)d_in[1];
  const float* W1    = (const float*)d_in[2];
  const float* b1    = (const float*)d_in[3];
  const float* w2    = (const float*)d_in[4];
  // d_in[5] = b2 (cancels in telescoped dE)
  const float* p1    = (const float*)d_in[6];
  const float* pb1   = (const float*)d_in[7];
  const float* p2    = (const float*)d_in[8];
  // d_in[9] = pb2 (cancels in telescoped dE)
  float* tab = (float*)d_ws;
  double* partials = (double*)((char*)d_ws + TAB_BYTES);
  float* out = (float*)d_out;

  hipLaunchKernelGGL(tfl_tabgen, dim3(NCELL / 256), dim3(256), 0, stream,
                     p1, pb1, p2, tab);
  hipLaunchKernelGGL(tfl_main6, dim3(NBLK), dim3(512), 0, stream,
                     data, tsnap, W1, b1, w2, tab, partials);
  hipLaunchKernelGGL(tfl_finalize, dim3(1), dim3(512), 0, stream, partials, out);
}